// Round 1
// baseline (12267.146 us; speedup 1.0000x reference)
//
#include <hip/hip_runtime.h>
#include <hip/hip_bf16.h>

// GRU encoder: B=128, K=512, I=512, H=512.
//   Phase A (per 64-step chunk): xg[k][b][g] = visual[b][k][:]·W_ih[g][:] + b_ih[g]  (bf16 MFMA)
//   Phase B (per 64-step chunk): sequential GRU steps, fp32, 8 groups x 32 WGs.
// Workspace layout: [ xg chunk 50,331,648 B | h ping-pong 524,288 B | cnt flags 262,144 B ]

#define CH 64                       // steps per chunk
#define XG_CHUNK_BYTES (CH * 128 * 1536 * 4)
#define HBUF_BYTES (2 * 128 * 512 * 4)
#define CNT_BYTES (512 * 128 * 4)

typedef float  floatx4 __attribute__((ext_vector_type(4)));
typedef short  shortx8 __attribute__((ext_vector_type(8)));

__device__ __forceinline__ unsigned short f2bf(float f) {
    unsigned int u = __float_as_uint(f);
    u = (u + 0x7FFFu + ((u >> 16) & 1u)) >> 16;   // RNE; inputs are finite normals
    return (unsigned short)u;
}

// ---------------- Phase A: x-gate GEMM (bf16 MFMA, 64x64 tiles) ----------------
// grid = (24 ntiles, 128 mtiles), block = 256 (4 waves; wave w owns rows 16w..16w+15)
__global__ __launch_bounds__(256)
void xgate_gemm(const float* __restrict__ vis, const float* __restrict__ Wih,
                const float* __restrict__ bih, float* __restrict__ xg, int kg0) {
    const int g0 = blockIdx.x * 64;         // gate-col base
    const int m0 = blockIdx.y * 64;         // chunk-local row base; m = kc*128 + b
    const int kc = m0 >> 7;                 // chunk-local timestep
    const int b0 = m0 & 127;                // batch base (0 or 64)
    const int kg = kg0 + kc;                // global timestep
    const int t = threadIdx.x;
    const int wave = t >> 6, lane = t & 63, quad = lane >> 4, l16 = lane & 15;

    __shared__ unsigned short Ast[64][40];  // 32 k + 8 pad (80B rows: 16B-aligned, conflict-free-ish)
    __shared__ unsigned short Bst[64][40];

    floatx4 acc[4] = {{0,0,0,0},{0,0,0,0},{0,0,0,0},{0,0,0,0}};

    for (int ki = 0; ki < 16; ++ki) {
        const int i0 = ki * 32;
        // stage A (visual rows) and B (W_ih rows), fp32->bf16
        #pragma unroll
        for (int rep = 0; rep < 2; ++rep) {
            const int r = (t >> 3) + rep * 32;
            const int c = (t & 7) * 4;
            float4 av = *(const float4*)(vis + ((size_t)(b0 + r) * 512 + kg) * 512 + i0 + c);
            ushort4 ab; ab.x = f2bf(av.x); ab.y = f2bf(av.y); ab.z = f2bf(av.z); ab.w = f2bf(av.w);
            *(ushort4*)&Ast[r][c] = ab;
            float4 bv = *(const float4*)(Wih + (size_t)(g0 + r) * 512 + i0 + c);
            ushort4 bb; bb.x = f2bf(bv.x); bb.y = f2bf(bv.y); bb.z = f2bf(bv.z); bb.w = f2bf(bv.w);
            *(ushort4*)&Bst[r][c] = bb;
        }
        __syncthreads();
        // A-frag: A[m=lane&15][k=quad*8+j]; B-frag likewise from B^T tile (rows = out-cols)
        shortx8 af = *(const shortx8*)(&Ast[wave * 16 + l16][quad * 8]);
        #pragma unroll
        for (int nb = 0; nb < 4; ++nb) {
            shortx8 bf = *(const shortx8*)(&Bst[nb * 16 + l16][quad * 8]);
            acc[nb] = __builtin_amdgcn_mfma_f32_16x16x32_bf16(af, bf, acc[nb], 0, 0, 0);
        }
        __syncthreads();
    }
    // C/D layout: col = lane&15, row = quad*4 + reg
    #pragma unroll
    for (int nb = 0; nb < 4; ++nb) {
        const int g = g0 + nb * 16 + l16;
        const float bi = bih[g];
        #pragma unroll
        for (int reg = 0; reg < 4; ++reg) {
            const int m = m0 + wave * 16 + quad * 4 + reg;
            xg[(size_t)m * 1536 + g] = acc[nb][reg] + bi;
        }
    }
}

// ---------------- Phase B: recurrent GRU steps (fp32) ----------------
// grid = 256: 8 groups x 32 WGs. Group owns batches [16g,16g+16); WG owns units [16w,16w+16).
// Thread (tb=t&15, tj=t>>4) computes the (batch tb, unit tj) r/z/n dots over full h.
// Sync: relaxed device-scope atomics for h exchange (sc1, coherence-point; no L2-wide
// invalidate so W_hh stays L2-resident); __syncthreads drains vmcnt before flag bump.
// Deadlock-safe: LDS ~38KB -> residency capacity >> 256 blocks.
__global__ __launch_bounds__(256)
void gru_rec(const float* __restrict__ Whh, const float* __restrict__ bhh,
             const float* __restrict__ xg, float* __restrict__ hbuf,
             unsigned int* __restrict__ cnt, float* __restrict__ out, int kg0) {
    const int wg = blockIdx.x, group = wg >> 5, wi = wg & 31;
    const int b0 = group * 16, u0 = wi * 16;
    const int t = threadIdx.x, tb = t & 15, tj = t >> 4;

    __shared__ float hL[16][516];     // staged h_prev, pad 516: 16B-aligned rows, <=2-way banks
    __shared__ float xgL[16][52];     // [batch][gate*16+unit]
    __shared__ float hnew[16][20];    // [batch][unit]
    __shared__ float bias[3][16];

    if (t < 48) bias[t >> 4][t & 15] = bhh[(t >> 4) * 512 + u0 + (t & 15)];

    // W_hh rows for this thread's unit (stream from L2 every step; 16-batch reuse per WG)
    const float4* wr4 = (const float4*)(Whh + (size_t)(u0 + tj) * 512);
    const float4* wz4 = (const float4*)(Whh + (size_t)(512 + u0 + tj) * 512);
    const float4* wn4 = (const float4*)(Whh + (size_t)(1024 + u0 + tj) * 512);

    for (int s = 0; s < CH; ++s) {
        const int kg = kg0 + s;
        if (kg == 0) {
            for (int idx = t; idx < 16 * 516; idx += 256) (&hL[0][0])[idx] = 0.f;
        } else {
            if (t < 16) {
                const unsigned int* fp = cnt + (size_t)(kg - 1) * 128 + b0 + t;
                while (__hip_atomic_load(fp, __ATOMIC_RELAXED, __HIP_MEMORY_SCOPE_AGENT) < 32u)
                    __builtin_amdgcn_s_sleep(1);
            }
            __syncthreads();
            const float* hsrc = hbuf + (size_t)((kg - 1) & 1) * (128 * 512);
            for (int idx = t; idx < 4096; idx += 256) {  // 16 batches x 512 fp32 as 8B coherent loads
                const int bl = idx >> 8, i = (idx & 255) * 2;
                unsigned long long v = __hip_atomic_load(
                    (const unsigned long long*)(hsrc + (size_t)(b0 + bl) * 512 + i),
                    __ATOMIC_RELAXED, __HIP_MEMORY_SCOPE_AGENT);
                float2 f = __builtin_bit_cast(float2, v);
                hL[bl][i] = f.x; hL[bl][i + 1] = f.y;
            }
        }
        const float* xgp = xg + (size_t)s * (128 * 1536) + (size_t)b0 * 1536;
        for (int idx = t; idx < 768; idx += 256) {
            const int bl = idx / 48, r = idx - bl * 48;
            xgL[bl][r] = xgp[bl * 1536 + (r >> 4) * 512 + u0 + (r & 15)];
        }
        __syncthreads();

        float ar = 0.f, az = 0.f, an = 0.f;
        const float4* h4 = (const float4*)(&hL[tb][0]);
        #pragma unroll 8
        for (int i4 = 0; i4 < 128; ++i4) {
            const float4 h = h4[i4];
            const float4 a = wr4[i4], b = wz4[i4], c = wn4[i4];
            ar += a.x * h.x + a.y * h.y + a.z * h.z + a.w * h.w;
            az += b.x * h.x + b.y * h.y + b.z * h.z + b.w * h.w;
            an += c.x * h.x + c.y * h.y + c.z * h.z + c.w * h.w;
        }
        const float hr = ar + bias[0][tj], hz = az + bias[1][tj], hn = an + bias[2][tj];
        const float xr = xgL[tb][tj], xz = xgL[tb][16 + tj], xn = xgL[tb][32 + tj];
        const float rg = 1.f / (1.f + __expf(-(xr + hr)));
        const float zg = 1.f / (1.f + __expf(-(xz + hz)));
        const float ng = tanhf(xn + rg * hn);
        const float hp = hL[tb][u0 + tj];
        hnew[tb][tj] = (1.f - zg) * ng + zg * hp;
        __syncthreads();

        if (t < 128) {  // publish 16 units x 16 batches as 8B coherent stores
            const int bl = t >> 3, pr = t & 7;
            float2 f; f.x = hnew[bl][pr * 2]; f.y = hnew[bl][pr * 2 + 1];
            const size_t off = (size_t)(b0 + bl) * 512 + u0 + pr * 2;
            __hip_atomic_store((unsigned long long*)(hbuf + (size_t)(kg & 1) * (128 * 512) + off),
                               __builtin_bit_cast(unsigned long long, f),
                               __ATOMIC_RELAXED, __HIP_MEMORY_SCOPE_AGENT);
            if (kg == 511) *(float2*)(out + off) = f;  // final h -> d_out (kernel-end flush)
        }
        __syncthreads();  // drains vmcnt: all stores complete at coherence point before flag
        if (t < 16)
            __hip_atomic_fetch_add(cnt + (size_t)kg * 128 + b0 + t, 1u,
                                   __ATOMIC_RELAXED, __HIP_MEMORY_SCOPE_AGENT);
    }
}

extern "C" void kernel_launch(void* const* d_in, const int* in_sizes, int n_in,
                              void* d_out, int out_size, void* d_ws, size_t ws_size,
                              hipStream_t stream) {
    const float* vis = (const float*)d_in[0];
    const float* Wih = (const float*)d_in[1];
    const float* Whh = (const float*)d_in[2];
    const float* bih = (const float*)d_in[3];
    const float* bhh = (const float*)d_in[4];
    float* out = (float*)d_out;

    char* ws = (char*)d_ws;
    float* xg = (float*)ws;
    float* hbuf = (float*)(ws + XG_CHUNK_BYTES);
    unsigned int* cnt = (unsigned int*)(ws + XG_CHUNK_BYTES + HBUF_BYTES);

    hipMemsetAsync(cnt, 0, CNT_BYTES, stream);

    for (int c = 0; c < 512 / CH; ++c) {
        const int kg0 = c * CH;
        xgate_gemm<<<dim3(24, 128), 256, 0, stream>>>(vis, Wih, bih, xg, kg0);
        gru_rec<<<256, 256, 0, stream>>>(Whh, bhh, xg, hbuf, cnt, out, kg0);
    }
}

// Round 3
// 5526.849 us; speedup vs baseline: 2.2196x; 2.2196x over previous
//
#include <hip/hip_runtime.h>
#include <hip/hip_bf16.h>

// GRU encoder: B=128, K=512, I=512, H=512.
//   Phase A (per 64-step chunk): xg[k][b][g] = visual[b][k][:]·W_ih[g][:] + b_ih[g]  (bf16 MFMA)
//   Phase B: persistent-LDS-weight MFMA recurrence.
//     64 WGs = 16 unit-groups (32 units each; W slice bf16 in LDS, ~100KB) x 4 batch-groups (32 batches).
//     h state fp32 in registers (thread owns fixed (b,u)); MFMA A-input = bf16 h via LLC.
// R3 fixes vs R2: (1) hb->hL reader copied only half of each row (ull = 4 shorts, not 8) ->
//     stale-LDS NaN into MFMA. (2) publish now LDS-bounce + 4B agent atomics (no partword CAS).
//     (3) flag = release/acquire.
// Workspace: [ xg chunk 50,331,648 B | hb bf16 262,144 B | hstate fp32 262,144 B | cnt 8,192 B ]

#define CH 64
#define XG_CHUNK_BYTES (CH * 128 * 1536 * 4)
#define HB_BYTES (2 * 128 * 512 * 2)
#define HSTATE_BYTES (128 * 512 * 4)
#define CNT_BYTES (512 * 4 * 4)

typedef float  floatx4 __attribute__((ext_vector_type(4)));
typedef short  shortx8 __attribute__((ext_vector_type(8)));

__device__ __forceinline__ unsigned short f2bf(float f) {
    unsigned int u = __float_as_uint(f);
    u = (u + 0x7FFFu + ((u >> 16) & 1u)) >> 16;   // RNE; finite normals only
    return (unsigned short)u;
}

// ---------------- Phase A: x-gate GEMM (bf16 MFMA, 64x64 tiles) ----------------
__global__ __launch_bounds__(256)
void xgate_gemm(const float* __restrict__ vis, const float* __restrict__ Wih,
                const float* __restrict__ bih, float* __restrict__ xg, int kg0) {
    const int g0 = blockIdx.x * 64;
    const int m0 = blockIdx.y * 64;
    const int kc = m0 >> 7;
    const int b0 = m0 & 127;
    const int kg = kg0 + kc;
    const int t = threadIdx.x;
    const int wave = t >> 6, lane = t & 63, quad = lane >> 4, l16 = lane & 15;

    __shared__ unsigned short Ast[64][40];
    __shared__ unsigned short Bst[64][40];

    floatx4 acc[4] = {{0,0,0,0},{0,0,0,0},{0,0,0,0},{0,0,0,0}};

    for (int ki = 0; ki < 16; ++ki) {
        const int i0 = ki * 32;
        #pragma unroll
        for (int rep = 0; rep < 2; ++rep) {
            const int r = (t >> 3) + rep * 32;
            const int c = (t & 7) * 4;
            float4 av = *(const float4*)(vis + ((size_t)(b0 + r) * 512 + kg) * 512 + i0 + c);
            ushort4 ab; ab.x = f2bf(av.x); ab.y = f2bf(av.y); ab.z = f2bf(av.z); ab.w = f2bf(av.w);
            *(ushort4*)&Ast[r][c] = ab;
            float4 bv = *(const float4*)(Wih + (size_t)(g0 + r) * 512 + i0 + c);
            ushort4 bb; bb.x = f2bf(bv.x); bb.y = f2bf(bv.y); bb.z = f2bf(bv.z); bb.w = f2bf(bv.w);
            *(ushort4*)&Bst[r][c] = bb;
        }
        __syncthreads();
        shortx8 af = *(const shortx8*)(&Ast[wave * 16 + l16][quad * 8]);
        #pragma unroll
        for (int nb = 0; nb < 4; ++nb) {
            shortx8 bf = *(const shortx8*)(&Bst[nb * 16 + l16][quad * 8]);
            acc[nb] = __builtin_amdgcn_mfma_f32_16x16x32_bf16(af, bf, acc[nb], 0, 0, 0);
        }
        __syncthreads();
    }
    #pragma unroll
    for (int nb = 0; nb < 4; ++nb) {
        const int g = g0 + nb * 16 + l16;
        const float bi = bih[g];
        #pragma unroll
        for (int reg = 0; reg < 4; ++reg) {
            const int m = m0 + wave * 16 + quad * 4 + reg;
            xg[(size_t)m * 1536 + g] = acc[nb][reg] + bi;
        }
    }
}

// ---------------- Phase B: recurrent GRU steps (MFMA, LDS-resident W) ----------------
// grid = 64: ug = wg&15 owns units [32ug,32ug+32), bg = wg>>4 owns batches [32bg,32bg+32).
// Wave (mt=wave&1, u16=wave>>1); thread owns (b = 32bg+16mt+4quad+reg, u = 32ug+16u16+l16),
// reg 0..3 — h state fp32 in registers across all 512 steps.
__global__ __launch_bounds__(256)
void gru_rec(const float* __restrict__ Whh, const float* __restrict__ bhh,
             const float* __restrict__ xg, unsigned short* __restrict__ hb,
             float* __restrict__ hstate, unsigned int* __restrict__ cnt,
             float* __restrict__ out, int kg0) {
    const int wg = blockIdx.x, ug = wg & 15, bg = wg >> 4;
    const int u0 = ug * 32, b0 = bg * 32;
    const int t = threadIdx.x, wave = t >> 6, lane = t & 63, quad = lane >> 4, l16 = lane & 15;
    const int mt = wave & 1, u16 = wave >> 1;
    const int b_base = b0 + mt * 16 + quad * 4;
    const int u = u0 + u16 * 16 + l16;

    __shared__ unsigned short Wl[2][3][16][520];   // [u16][gate][n][k] bf16
    __shared__ unsigned short hL[32][520];         // [batch][unit] bf16
    __shared__ unsigned short hpub[32][32];        // publish bounce [b_local][u_local]

    // --- one-time: W_hh slice -> LDS bf16 ---
    for (int j = t; j < 12288; j += 256) {         // 2*3*16*128 float4s
        const int k4 = j & 127, n = (j >> 7) & 15, g = (j >> 11) % 3, ub = (j >> 11) / 3;
        float4 w = *(const float4*)(Whh + ((size_t)(g * 512 + u0 + ub * 16 + n)) * 512 + k4 * 4);
        ushort4 wb; wb.x = f2bf(w.x); wb.y = f2bf(w.y); wb.z = f2bf(w.z); wb.w = f2bf(w.w);
        *(ushort4*)&Wl[ub][g][n][k4 * 4] = wb;
    }
    const float bhr = bhh[u], bhz = bhh[512 + u], bhn = bhh[1024 + u];

    float hp[4];
    if (kg0 == 0) {
        hp[0] = hp[1] = hp[2] = hp[3] = 0.f;
        for (int j = t; j < 32 * 520; j += 256) (&hL[0][0])[j] = 0;
    } else {
        #pragma unroll
        for (int reg = 0; reg < 4; ++reg) hp[reg] = hstate[(size_t)(b_base + reg) * 512 + u];
    }
    __syncthreads();

    for (int s = 0; s < CH; ++s) {
        const int kg = kg0 + s;
        // prefetch x-gates (h-independent) before the flag wait
        float xr[4], xz[4], xn[4];
        #pragma unroll
        for (int reg = 0; reg < 4; ++reg) {
            const float* xgp = xg + ((size_t)s * 128 + b_base + reg) * 1536 + u;
            xr[reg] = xgp[0]; xz[reg] = xgp[512]; xn[reg] = xgp[1024];
        }

        if (kg > 0) {
            if (t == 0) {
                const unsigned int* fp = cnt + (size_t)(kg - 1) * 4 + bg;
                while (__hip_atomic_load(fp, __ATOMIC_ACQUIRE, __HIP_MEMORY_SCOPE_AGENT) < 16u)
                    __builtin_amdgcn_s_sleep(1);
            }
            __syncthreads();
            const unsigned short* hsrc = hb + (size_t)((kg - 1) & 1) * (128 * 512);
            // 32 rows x 512 shorts = 128 ull per row (ull = 4 shorts!)
            for (int idx = t; idx < 4096; idx += 256) {
                const int row = idx >> 7, col = (idx & 127) * 4;
                unsigned long long v = __hip_atomic_load(
                    (const unsigned long long*)(hsrc + (size_t)(b0 + row) * 512 + col),
                    __ATOMIC_RELAXED, __HIP_MEMORY_SCOPE_AGENT);
                *(unsigned long long*)&hL[row][col] = v;
            }
        }
        __syncthreads();

        floatx4 aR = {0,0,0,0}, aZ = {0,0,0,0}, aN = {0,0,0,0};
        #pragma unroll
        for (int k = 0; k < 16; ++k) {
            const int kc = k * 32 + quad * 8;
            shortx8 af = *(const shortx8*)&hL[mt * 16 + l16][kc];
            shortx8 bR = *(const shortx8*)&Wl[u16][0][l16][kc];
            shortx8 bZ = *(const shortx8*)&Wl[u16][1][l16][kc];
            shortx8 bN = *(const shortx8*)&Wl[u16][2][l16][kc];
            aR = __builtin_amdgcn_mfma_f32_16x16x32_bf16(af, bR, aR, 0, 0, 0);
            aZ = __builtin_amdgcn_mfma_f32_16x16x32_bf16(af, bZ, aZ, 0, 0, 0);
            aN = __builtin_amdgcn_mfma_f32_16x16x32_bf16(af, bN, aN, 0, 0, 0);
        }

        #pragma unroll
        for (int reg = 0; reg < 4; ++reg) {
            const float r = 1.f / (1.f + __expf(-(xr[reg] + aR[reg] + bhr)));
            const float z = 1.f / (1.f + __expf(-(xz[reg] + aZ[reg] + bhz)));
            const float n = tanhf(xn[reg] + r * (aN[reg] + bhn));
            const float h = (1.f - z) * n + z * hp[reg];
            hp[reg] = h;
            hpub[mt * 16 + quad * 4 + reg][u16 * 16 + l16] = f2bf(h);
            if (kg == 511) out[(size_t)(b_base + reg) * 512 + u] = h;
        }
        __syncthreads();

        // publish 32x32 bf16 as 4B agent atomics (512 dwords)
        unsigned short* hdst = hb + (size_t)(kg & 1) * (128 * 512);
        for (int idx = t; idx < 512; idx += 256) {
            const int row = idx >> 4, c = idx & 15;
            unsigned int v = *(const unsigned int*)&hpub[row][c * 2];
            __hip_atomic_store((unsigned int*)(hdst + (size_t)(b0 + row) * 512 + u0 + c * 2),
                               v, __ATOMIC_RELAXED, __HIP_MEMORY_SCOPE_AGENT);
        }
        __syncthreads();   // drains vmcnt: publishes at coherence point before flag
        if (t == 0)
            __hip_atomic_fetch_add(cnt + (size_t)kg * 4 + bg, 1u,
                                   __ATOMIC_RELEASE, __HIP_MEMORY_SCOPE_AGENT);
    }

    // carry fp32 state across chunk launches (kernel-boundary visibility)
    #pragma unroll
    for (int reg = 0; reg < 4; ++reg)
        hstate[(size_t)(b_base + reg) * 512 + u] = hp[reg];
}

extern "C" void kernel_launch(void* const* d_in, const int* in_sizes, int n_in,
                              void* d_out, int out_size, void* d_ws, size_t ws_size,
                              hipStream_t stream) {
    const float* vis = (const float*)d_in[0];
    const float* Wih = (const float*)d_in[1];
    const float* Whh = (const float*)d_in[2];
    const float* bih = (const float*)d_in[3];
    const float* bhh = (const float*)d_in[4];
    float* out = (float*)d_out;

    char* ws = (char*)d_ws;
    float* xg = (float*)ws;
    unsigned short* hb = (unsigned short*)(ws + XG_CHUNK_BYTES);
    float* hstate = (float*)(ws + XG_CHUNK_BYTES + HB_BYTES);
    unsigned int* cnt = (unsigned int*)(ws + XG_CHUNK_BYTES + HB_BYTES + HSTATE_BYTES);

    hipMemsetAsync(cnt, 0, CNT_BYTES, stream);

    for (int c = 0; c < 512 / CH; ++c) {
        const int kg0 = c * CH;
        xgate_gemm<<<dim3(24, 128), 256, 0, stream>>>(vis, Wih, bih, xg, kg0);
        gru_rec<<<64, 256, 0, stream>>>(Whh, bhh, xg, hb, hstate, cnt, out, kg0);
    }
}

// Round 4
// 4076.013 us; speedup vs baseline: 3.0096x; 1.3559x over previous
//
#include <hip/hip_runtime.h>
#include <hip/hip_bf16.h>

// GRU encoder: B=128, K=512, I=512, H=512.
//   Phase A (per 64-step chunk): xg = visual·W_ihᵀ + b_ih  (bf16 MFMA, unchanged from R3)
//   Phase B: recurrence, 64 WGs = 16 unit-groups x 4 batch-groups.
//     R4: W_hh in VGPRs (192/lane), A-frags direct from LLC, relaxed poll + one acquire
//     fence, register publish via shfl_xor pairs. No LDS in the hot loop.
// Workspace: [ xg chunk 50,331,648 B | hb bf16 262,144 B | hstate fp32 262,144 B | cnt 8,192 B ]

#define CH 64
#define XG_CHUNK_BYTES (CH * 128 * 1536 * 4)
#define HB_BYTES (2 * 128 * 512 * 2)
#define HSTATE_BYTES (128 * 512 * 4)
#define CNT_BYTES (512 * 4 * 4)

typedef float  floatx4 __attribute__((ext_vector_type(4)));
typedef short  shortx8 __attribute__((ext_vector_type(8)));

__device__ __forceinline__ unsigned short f2bf(float f) {
    unsigned int u = __float_as_uint(f);
    u = (u + 0x7FFFu + ((u >> 16) & 1u)) >> 16;   // RNE; finite normals only
    return (unsigned short)u;
}

// ---------------- Phase A: x-gate GEMM (bf16 MFMA, 64x64 tiles) ----------------
__global__ __launch_bounds__(256)
void xgate_gemm(const float* __restrict__ vis, const float* __restrict__ Wih,
                const float* __restrict__ bih, float* __restrict__ xg, int kg0) {
    const int g0 = blockIdx.x * 64;
    const int m0 = blockIdx.y * 64;
    const int kc = m0 >> 7;
    const int b0 = m0 & 127;
    const int kg = kg0 + kc;
    const int t = threadIdx.x;
    const int wave = t >> 6, lane = t & 63, quad = lane >> 4, l16 = lane & 15;

    __shared__ unsigned short Ast[64][40];
    __shared__ unsigned short Bst[64][40];

    floatx4 acc[4] = {{0,0,0,0},{0,0,0,0},{0,0,0,0},{0,0,0,0}};

    for (int ki = 0; ki < 16; ++ki) {
        const int i0 = ki * 32;
        #pragma unroll
        for (int rep = 0; rep < 2; ++rep) {
            const int r = (t >> 3) + rep * 32;
            const int c = (t & 7) * 4;
            float4 av = *(const float4*)(vis + ((size_t)(b0 + r) * 512 + kg) * 512 + i0 + c);
            ushort4 ab; ab.x = f2bf(av.x); ab.y = f2bf(av.y); ab.z = f2bf(av.z); ab.w = f2bf(av.w);
            *(ushort4*)&Ast[r][c] = ab;
            float4 bv = *(const float4*)(Wih + (size_t)(g0 + r) * 512 + i0 + c);
            ushort4 bb; bb.x = f2bf(bv.x); bb.y = f2bf(bv.y); bb.z = f2bf(bv.z); bb.w = f2bf(bv.w);
            *(ushort4*)&Bst[r][c] = bb;
        }
        __syncthreads();
        shortx8 af = *(const shortx8*)(&Ast[wave * 16 + l16][quad * 8]);
        #pragma unroll
        for (int nb = 0; nb < 4; ++nb) {
            shortx8 bf = *(const shortx8*)(&Bst[nb * 16 + l16][quad * 8]);
            acc[nb] = __builtin_amdgcn_mfma_f32_16x16x32_bf16(af, bf, acc[nb], 0, 0, 0);
        }
        __syncthreads();
    }
    #pragma unroll
    for (int nb = 0; nb < 4; ++nb) {
        const int g = g0 + nb * 16 + l16;
        const float bi = bih[g];
        #pragma unroll
        for (int reg = 0; reg < 4; ++reg) {
            const int m = m0 + wave * 16 + quad * 4 + reg;
            xg[(size_t)m * 1536 + g] = acc[nb][reg] + bi;
        }
    }
}

// ---------------- Phase B: recurrent GRU steps ----------------
// grid = 64: ug = wg&15 owns units [32ug,32ug+32), bg = wg>>4 owns batches [32bg,32bg+32).
// Wave (mt=wave&1, u16=wave>>1); thread owns (b = b_base+reg, u), h state fp32 in regs.
// W_hh slice bf16 in VGPRs: w[3 gates][16 ktiles] shortx8 per lane (B-frag layout).
__global__ __launch_bounds__(256, 1)
void gru_rec(const float* __restrict__ Whh, const float* __restrict__ bhh,
             const float* __restrict__ xg, unsigned short* __restrict__ hb,
             float* __restrict__ hstate, unsigned int* __restrict__ cnt,
             float* __restrict__ out, int kg0) {
    const int wg = blockIdx.x, ug = wg & 15, bg = wg >> 4;
    const int u0 = ug * 32, b0 = bg * 32;
    const int t = threadIdx.x, wave = t >> 6, lane = t & 63, quad = lane >> 4, l16 = lane & 15;
    const int mt = wave & 1, u16 = wave >> 1;
    const int b_base = b0 + mt * 16 + quad * 4;
    const int u = u0 + u16 * 16 + l16;

    // --- one-time: W_hh B-fragments -> VGPRs (lane = unit row l16, k = quad*8+j) ---
    shortx8 w[3][16];
    #pragma unroll
    for (int g = 0; g < 3; ++g) {
        #pragma unroll
        for (int kt = 0; kt < 16; ++kt) {
            const float* p = Whh + ((size_t)(g * 512 + u)) * 512 + kt * 32 + quad * 8;
            float4 a = *(const float4*)p;
            float4 b = *(const float4*)(p + 4);
            shortx8 v;
            v[0] = (short)f2bf(a.x); v[1] = (short)f2bf(a.y);
            v[2] = (short)f2bf(a.z); v[3] = (short)f2bf(a.w);
            v[4] = (short)f2bf(b.x); v[5] = (short)f2bf(b.y);
            v[6] = (short)f2bf(b.z); v[7] = (short)f2bf(b.w);
            w[g][kt] = v;
        }
    }
    const float bhr = bhh[u], bhz = bhh[512 + u], bhn = bhh[1024 + u];

    float hp[4];
    if (kg0 == 0) {
        hp[0] = hp[1] = hp[2] = hp[3] = 0.f;
    } else {
        #pragma unroll
        for (int reg = 0; reg < 4; ++reg) hp[reg] = hstate[(size_t)(b_base + reg) * 512 + u];
    }

    for (int s = 0; s < CH; ++s) {
        const int kg = kg0 + s;
        // prefetch x-gates (h-independent) before the flag wait
        float xr[4], xz[4], xn[4];
        #pragma unroll
        for (int reg = 0; reg < 4; ++reg) {
            const float* xgp = xg + ((size_t)s * 128 + b_base + reg) * 1536 + u;
            xr[reg] = xgp[0]; xz[reg] = xgp[512]; xn[reg] = xgp[1024];
        }

        // A-fragments: h of my 16 batch rows, direct from LLC (publishers wrote sc1)
        shortx8 af[16];
        if (kg > 0) {
            if (t == 0) {
                const unsigned int* fp = cnt + (size_t)(kg - 1) * 4 + bg;
                while (__hip_atomic_load(fp, __ATOMIC_RELAXED, __HIP_MEMORY_SCOPE_AGENT) < 16u)
                    __builtin_amdgcn_s_sleep(1);
            }
            __syncthreads();
            __builtin_amdgcn_fence(__ATOMIC_ACQUIRE, "agent");   // inv L1/L2 once
            const unsigned short* hsrc = hb + (size_t)((kg - 1) & 1) * (128 * 512)
                                            + (size_t)(b0 + mt * 16 + l16) * 512 + quad * 8;
            #pragma unroll
            for (int kt = 0; kt < 16; ++kt)
                af[kt] = *(const shortx8*)(hsrc + kt * 32);
        } else {
            #pragma unroll
            for (int kt = 0; kt < 16; ++kt)
                af[kt] = (shortx8){0, 0, 0, 0, 0, 0, 0, 0};
        }

        floatx4 aR = {0,0,0,0}, aZ = {0,0,0,0}, aN = {0,0,0,0};
        #pragma unroll
        for (int kt = 0; kt < 16; ++kt) {
            aR = __builtin_amdgcn_mfma_f32_16x16x32_bf16(af[kt], w[0][kt], aR, 0, 0, 0);
            aZ = __builtin_amdgcn_mfma_f32_16x16x32_bf16(af[kt], w[1][kt], aZ, 0, 0, 0);
            aN = __builtin_amdgcn_mfma_f32_16x16x32_bf16(af[kt], w[2][kt], aN, 0, 0, 0);
        }

        unsigned short* hdst = hb + (size_t)(kg & 1) * (128 * 512);
        #pragma unroll
        for (int reg = 0; reg < 4; ++reg) {
            const float r = 1.f / (1.f + __expf(-(xr[reg] + aR[reg] + bhr)));
            const float z = 1.f / (1.f + __expf(-(xz[reg] + aZ[reg] + bhz)));
            const float n = tanhf(xn[reg] + r * (aN[reg] + bhn));
            const float h = (1.f - z) * n + z * hp[reg];
            hp[reg] = h;
            // pack (u, u+1) pair via shfl_xor; even lane stores the dword (sc1 write-through)
            const float hο = __shfl_xor(h, 1);
            if (!(lane & 1)) {
                unsigned int pk = (unsigned int)f2bf(h) | ((unsigned int)f2bf(hο) << 16);
                __hip_atomic_store((unsigned int*)(hdst + (size_t)(b_base + reg) * 512 + u),
                                   pk, __ATOMIC_RELAXED, __HIP_MEMORY_SCOPE_AGENT);
            }
            if (kg == 511) out[(size_t)(b_base + reg) * 512 + u] = h;
        }
        __syncthreads();   // vmcnt(0): all waves' sc1 publishes acked at LLC before flag
        if (t == 0)
            __hip_atomic_fetch_add(cnt + (size_t)kg * 4 + bg, 1u,
                                   __ATOMIC_RELAXED, __HIP_MEMORY_SCOPE_AGENT);
    }

    // carry fp32 state across chunk launches (kernel-end flush handles visibility)
    #pragma unroll
    for (int reg = 0; reg < 4; ++reg)
        hstate[(size_t)(b_base + reg) * 512 + u] = hp[reg];
}

extern "C" void kernel_launch(void* const* d_in, const int* in_sizes, int n_in,
                              void* d_out, int out_size, void* d_ws, size_t ws_size,
                              hipStream_t stream) {
    const float* vis = (const float*)d_in[0];
    const float* Wih = (const float*)d_in[1];
    const float* Whh = (const float*)d_in[2];
    const float* bih = (const float*)d_in[3];
    const float* bhh = (const float*)d_in[4];
    float* out = (float*)d_out;

    char* ws = (char*)d_ws;
    float* xg = (float*)ws;
    unsigned short* hb = (unsigned short*)(ws + XG_CHUNK_BYTES);
    float* hstate = (float*)(ws + XG_CHUNK_BYTES + HB_BYTES);
    unsigned int* cnt = (unsigned int*)(ws + XG_CHUNK_BYTES + HB_BYTES + HSTATE_BYTES);

    hipMemsetAsync(cnt, 0, CNT_BYTES, stream);

    for (int c = 0; c < 512 / CH; ++c) {
        const int kg0 = c * CH;
        xgate_gemm<<<dim3(24, 128), 256, 0, stream>>>(vis, Wih, bih, xg, kg0);
        gru_rec<<<64, 256, 0, stream>>>(Whh, bhh, xg, hb, hstate, cnt, out, kg0);
    }
}

// Round 5
// 3878.350 us; speedup vs baseline: 3.1630x; 1.0510x over previous
//
#include <hip/hip_runtime.h>
#include <hip/hip_bf16.h>

// GRU encoder: B=128, K=512, I=512, H=512.
//   Phase A (per 64-step chunk): xg = visual·W_ihᵀ + b_ih  (bf16 MFMA)
//   Phase B: recurrence, 64 WGs = 16 unit-groups x 4 batch-groups (independent domains).
//     R5: fence-free h exchange via relaxed agent atomic loads; per-wave flag poll
//     (no after-poll barrier); flags padded to 64B lines. W_hh in VGPRs; h fp32 in regs.
// Workspace: [ xg chunk 50,331,648 B | hb bf16 262,144 B | hstate fp32 262,144 B | cnt 131,072 B ]

#define CH 64
#define XG_CHUNK_BYTES (CH * 128 * 1536 * 4)
#define HB_BYTES (2 * 128 * 512 * 2)
#define HSTATE_BYTES (128 * 512 * 4)
#define CNT_STRIDE 16                       // dwords: one 64B line per (step, bg)
#define CNT_BYTES (512 * 4 * CNT_STRIDE * 4)

typedef float  floatx4 __attribute__((ext_vector_type(4)));
typedef short  shortx8 __attribute__((ext_vector_type(8)));

__device__ __forceinline__ unsigned short f2bf(float f) {
    unsigned int u = __float_as_uint(f);
    u = (u + 0x7FFFu + ((u >> 16) & 1u)) >> 16;   // RNE; finite normals only
    return (unsigned short)u;
}

// ---------------- Phase A: x-gate GEMM (bf16 MFMA, 64x64 tiles) ----------------
__global__ __launch_bounds__(256)
void xgate_gemm(const float* __restrict__ vis, const float* __restrict__ Wih,
                const float* __restrict__ bih, float* __restrict__ xg, int kg0) {
    const int g0 = blockIdx.x * 64;
    const int m0 = blockIdx.y * 64;
    const int kc = m0 >> 7;
    const int b0 = m0 & 127;
    const int kg = kg0 + kc;
    const int t = threadIdx.x;
    const int wave = t >> 6, lane = t & 63, quad = lane >> 4, l16 = lane & 15;

    __shared__ unsigned short Ast[64][40];
    __shared__ unsigned short Bst[64][40];

    floatx4 acc[4] = {{0,0,0,0},{0,0,0,0},{0,0,0,0},{0,0,0,0}};

    for (int ki = 0; ki < 16; ++ki) {
        const int i0 = ki * 32;
        #pragma unroll
        for (int rep = 0; rep < 2; ++rep) {
            const int r = (t >> 3) + rep * 32;
            const int c = (t & 7) * 4;
            float4 av = *(const float4*)(vis + ((size_t)(b0 + r) * 512 + kg) * 512 + i0 + c);
            ushort4 ab; ab.x = f2bf(av.x); ab.y = f2bf(av.y); ab.z = f2bf(av.z); ab.w = f2bf(av.w);
            *(ushort4*)&Ast[r][c] = ab;
            float4 bv = *(const float4*)(Wih + (size_t)(g0 + r) * 512 + i0 + c);
            ushort4 bb; bb.x = f2bf(bv.x); bb.y = f2bf(bv.y); bb.z = f2bf(bv.z); bb.w = f2bf(bv.w);
            *(ushort4*)&Bst[r][c] = bb;
        }
        __syncthreads();
        shortx8 af = *(const shortx8*)(&Ast[wave * 16 + l16][quad * 8]);
        #pragma unroll
        for (int nb = 0; nb < 4; ++nb) {
            shortx8 bf = *(const shortx8*)(&Bst[nb * 16 + l16][quad * 8]);
            acc[nb] = __builtin_amdgcn_mfma_f32_16x16x32_bf16(af, bf, acc[nb], 0, 0, 0);
        }
        __syncthreads();
    }
    #pragma unroll
    for (int nb = 0; nb < 4; ++nb) {
        const int g = g0 + nb * 16 + l16;
        const float bi = bih[g];
        #pragma unroll
        for (int reg = 0; reg < 4; ++reg) {
            const int m = m0 + wave * 16 + quad * 4 + reg;
            xg[(size_t)m * 1536 + g] = acc[nb][reg] + bi;
        }
    }
}

// ---------------- Phase B: recurrent GRU steps ----------------
// grid = 64: ug = wg&15 owns units [32ug,32ug+32), bg = wg>>4 owns batches [32bg,32bg+32).
// Wave (mt=wave&1, u16=wave>>1); thread owns (b = b_base+reg, u); h state fp32 in regs.
// W_hh slice bf16 in VGPRs. Per step: every wave polls flag(kg-1,bg) itself (no barrier),
// pulls af via relaxed agent 8B atomic loads (coherent, no fence), MFMA, gates, publishes
// sc1 dword pairs; one barrier (vmcnt drain) then t0 bumps flag(kg,bg).
__global__ __launch_bounds__(256, 1)
void gru_rec(const float* __restrict__ Whh, const float* __restrict__ bhh,
             const float* __restrict__ xg, unsigned short* __restrict__ hb,
             float* __restrict__ hstate, unsigned int* __restrict__ cnt,
             float* __restrict__ out, int kg0) {
    const int wg = blockIdx.x, ug = wg & 15, bg = wg >> 4;
    const int u0 = ug * 32, b0 = bg * 32;
    const int t = threadIdx.x, wave = t >> 6, lane = t & 63, quad = lane >> 4, l16 = lane & 15;
    const int mt = wave & 1, u16 = wave >> 1;
    const int b_base = b0 + mt * 16 + quad * 4;
    const int u = u0 + u16 * 16 + l16;

    // --- one-time: W_hh B-fragments -> VGPRs (lane = unit row l16, k = quad*8+j) ---
    shortx8 w[3][16];
    #pragma unroll
    for (int g = 0; g < 3; ++g) {
        #pragma unroll
        for (int kt = 0; kt < 16; ++kt) {
            const float* p = Whh + ((size_t)(g * 512 + u)) * 512 + kt * 32 + quad * 8;
            float4 a = *(const float4*)p;
            float4 b = *(const float4*)(p + 4);
            shortx8 v;
            v[0] = (short)f2bf(a.x); v[1] = (short)f2bf(a.y);
            v[2] = (short)f2bf(a.z); v[3] = (short)f2bf(a.w);
            v[4] = (short)f2bf(b.x); v[5] = (short)f2bf(b.y);
            v[6] = (short)f2bf(b.z); v[7] = (short)f2bf(b.w);
            w[g][kt] = v;
        }
    }
    const float bhr = bhh[u], bhz = bhh[512 + u], bhn = bhh[1024 + u];

    float hp[4];
    if (kg0 == 0) {
        hp[0] = hp[1] = hp[2] = hp[3] = 0.f;
    } else {
        #pragma unroll
        for (int reg = 0; reg < 4; ++reg) hp[reg] = hstate[(size_t)(b_base + reg) * 512 + u];
    }

    for (int s = 0; s < CH; ++s) {
        const int kg = kg0 + s;
        // prefetch x-gates (h-independent) before the flag wait
        float xr[4], xz[4], xn[4];
        #pragma unroll
        for (int reg = 0; reg < 4; ++reg) {
            const float* xgp = xg + ((size_t)s * 128 + b_base + reg) * 1536 + u;
            xr[reg] = xgp[0]; xz[reg] = xgp[512]; xn[reg] = xgp[1024];
        }

        // A-fragments: h rows direct from LLC via relaxed agent atomics (no fence needed)
        union { unsigned long long u8[2]; shortx8 v; } af[16];
        if (kg > 0) {
            // per-wave poll: same-address load coalesces to one request per wave
            const unsigned int* fp = cnt + ((size_t)(kg - 1) * 4 + bg) * CNT_STRIDE;
            while (__hip_atomic_load(fp, __ATOMIC_RELAXED, __HIP_MEMORY_SCOPE_AGENT) < 16u)
                __builtin_amdgcn_s_sleep(1);
            const unsigned short* hsrc = hb + (size_t)((kg - 1) & 1) * (128 * 512)
                                            + (size_t)(b0 + mt * 16 + l16) * 512 + quad * 8;
            #pragma unroll
            for (int kt = 0; kt < 16; ++kt) {
                af[kt].u8[0] = __hip_atomic_load((const unsigned long long*)(hsrc + kt * 32),
                                                 __ATOMIC_RELAXED, __HIP_MEMORY_SCOPE_AGENT);
                af[kt].u8[1] = __hip_atomic_load((const unsigned long long*)(hsrc + kt * 32 + 4),
                                                 __ATOMIC_RELAXED, __HIP_MEMORY_SCOPE_AGENT);
            }
        } else {
            #pragma unroll
            for (int kt = 0; kt < 16; ++kt) { af[kt].u8[0] = 0ull; af[kt].u8[1] = 0ull; }
        }

        floatx4 aR = {0,0,0,0}, aZ = {0,0,0,0}, aN = {0,0,0,0};
        #pragma unroll
        for (int kt = 0; kt < 16; ++kt) {
            aR = __builtin_amdgcn_mfma_f32_16x16x32_bf16(af[kt].v, w[0][kt], aR, 0, 0, 0);
            aZ = __builtin_amdgcn_mfma_f32_16x16x32_bf16(af[kt].v, w[1][kt], aZ, 0, 0, 0);
            aN = __builtin_amdgcn_mfma_f32_16x16x32_bf16(af[kt].v, w[2][kt], aN, 0, 0, 0);
        }

        unsigned short* hdst = hb + (size_t)(kg & 1) * (128 * 512);
        #pragma unroll
        for (int reg = 0; reg < 4; ++reg) {
            const float r = 1.f / (1.f + __expf(-(xr[reg] + aR[reg] + bhr)));
            const float z = 1.f / (1.f + __expf(-(xz[reg] + aZ[reg] + bhz)));
            const float n = tanhf(xn[reg] + r * (aN[reg] + bhn));
            const float h = (1.f - z) * n + z * hp[reg];
            hp[reg] = h;
            // pack (u, u+1) pair via shfl_xor; even lane stores the dword (sc1 write-through)
            const float h_odd = __shfl_xor(h, 1);
            if (!(lane & 1)) {
                unsigned int pk = (unsigned int)f2bf(h) | ((unsigned int)f2bf(h_odd) << 16);
                __hip_atomic_store((unsigned int*)(hdst + (size_t)(b_base + reg) * 512 + u),
                                   pk, __ATOMIC_RELAXED, __HIP_MEMORY_SCOPE_AGENT);
            }
            if (kg == 511) out[(size_t)(b_base + reg) * 512 + u] = h;
        }
        __syncthreads();   // vmcnt(0): all 4 waves' sc1 publishes acked at LLC before flag
        if (t == 0)
            __hip_atomic_fetch_add(cnt + ((size_t)kg * 4 + bg) * CNT_STRIDE, 1u,
                                   __ATOMIC_RELAXED, __HIP_MEMORY_SCOPE_AGENT);
    }

    // carry fp32 state across chunk launches (kernel-end flush handles visibility)
    #pragma unroll
    for (int reg = 0; reg < 4; ++reg)
        hstate[(size_t)(b_base + reg) * 512 + u] = hp[reg];
}

extern "C" void kernel_launch(void* const* d_in, const int* in_sizes, int n_in,
                              void* d_out, int out_size, void* d_ws, size_t ws_size,
                              hipStream_t stream) {
    const float* vis = (const float*)d_in[0];
    const float* Wih = (const float*)d_in[1];
    const float* Whh = (const float*)d_in[2];
    const float* bih = (const float*)d_in[3];
    const float* bhh = (const float*)d_in[4];
    float* out = (float*)d_out;

    char* ws = (char*)d_ws;
    float* xg = (float*)ws;
    unsigned short* hb = (unsigned short*)(ws + XG_CHUNK_BYTES);
    float* hstate = (float*)(ws + XG_CHUNK_BYTES + HB_BYTES);
    unsigned int* cnt = (unsigned int*)(ws + XG_CHUNK_BYTES + HB_BYTES + HSTATE_BYTES);

    hipMemsetAsync(cnt, 0, CNT_BYTES, stream);

    for (int c = 0; c < 512 / CH; ++c) {
        const int kg0 = c * CH;
        xgate_gemm<<<dim3(24, 128), 256, 0, stream>>>(vis, Wih, bih, xg, kg0);
        gru_rec<<<64, 256, 0, stream>>>(Whh, bhh, xg, hb, hstate, cnt, out, kg0);
    }
}

// Round 6
// 3661.463 us; speedup vs baseline: 3.3503x; 1.0592x over previous
//
#include <hip/hip_runtime.h>
#include <hip/hip_bf16.h>

// GRU encoder: B=128, K=512, I=512, H=512.
// R6: single role-split kernel per chunk (CH=32):
//   blocks 0..63  : recurrence for chunk c (R5 scheme: W_hh in VGPRs, fence-free relaxed
//                   agent-atomic h exchange, per-wave flag poll, padded flag lines)
//   blocks 64..255: x-gate GEMM for chunk c+1 into the other xg buffer (concurrent; no
//                   cross-role dependency — kernel boundary orders xg visibility)
// Dispatch 0 = GEMM only (chunk 0); dispatch 16 = rec only.
// Workspace: [ xg0 25,165,824 | xg1 25,165,824 | hb 262,144 | hstate 262,144 | cnt 131,072 ]
//            = 50,987,008 B (identical footprint to R5).

#define CH 32
#define XG_BYTES (CH * 128 * 1536 * 4)
#define HB_BYTES (2 * 128 * 512 * 2)
#define HSTATE_BYTES (128 * 512 * 4)
#define CNT_STRIDE 16                       // dwords: one 64B line per (step, bg)
#define CNT_BYTES (512 * 4 * CNT_STRIDE * 4)

typedef float  floatx4 __attribute__((ext_vector_type(4)));
typedef short  shortx8 __attribute__((ext_vector_type(8)));

__device__ __forceinline__ unsigned short f2bf(float f) {
    unsigned int u = __float_as_uint(f);
    u = (u + 0x7FFFu + ((u >> 16) & 1u)) >> 16;   // RNE; finite normals only
    return (unsigned short)u;
}

__global__ __launch_bounds__(256, 1)
void gru_fused(const float* __restrict__ vis, const float* __restrict__ Wih,
               const float* __restrict__ bih, const float* __restrict__ Whh,
               const float* __restrict__ bhh,
               const float* __restrict__ xgR, float* __restrict__ xgW,
               unsigned short* __restrict__ hb, float* __restrict__ hstate,
               unsigned int* __restrict__ cnt, float* __restrict__ out,
               int kg0, int gemm_kg0, int do_rec, int do_gemm) {
    __shared__ unsigned short Ast[64][40];   // gemm role only
    __shared__ unsigned short Bst[64][40];

    const int bx = blockIdx.x;
    const int t = threadIdx.x;
    const int wave = t >> 6, lane = t & 63, quad = lane >> 4, l16 = lane & 15;

    if (do_rec && bx < 64) {
        // ================= REC ROLE (R5 scheme, unchanged numerics) =================
        const int ug = bx & 15, bg = bx >> 4;
        const int u0 = ug * 32, b0 = bg * 32;
        const int mt = wave & 1, u16 = wave >> 1;
        const int b_base = b0 + mt * 16 + quad * 4;
        const int u = u0 + u16 * 16 + l16;

        // one-time: W_hh B-fragments -> VGPRs (lane = unit row l16, k = quad*8+j)
        shortx8 w[3][16];
        #pragma unroll
        for (int g = 0; g < 3; ++g) {
            #pragma unroll
            for (int kt = 0; kt < 16; ++kt) {
                const float* p = Whh + ((size_t)(g * 512 + u)) * 512 + kt * 32 + quad * 8;
                float4 a = *(const float4*)p;
                float4 b = *(const float4*)(p + 4);
                shortx8 v;
                v[0] = (short)f2bf(a.x); v[1] = (short)f2bf(a.y);
                v[2] = (short)f2bf(a.z); v[3] = (short)f2bf(a.w);
                v[4] = (short)f2bf(b.x); v[5] = (short)f2bf(b.y);
                v[6] = (short)f2bf(b.z); v[7] = (short)f2bf(b.w);
                w[g][kt] = v;
            }
        }
        const float bhr = bhh[u], bhz = bhh[512 + u], bhn = bhh[1024 + u];

        float hp[4];
        if (kg0 == 0) {
            hp[0] = hp[1] = hp[2] = hp[3] = 0.f;
        } else {
            #pragma unroll
            for (int reg = 0; reg < 4; ++reg) hp[reg] = hstate[(size_t)(b_base + reg) * 512 + u];
        }

        for (int s = 0; s < CH; ++s) {
            const int kg = kg0 + s;
            // x-gate loads issue before the poll; poll+af+MFMA (>=1.5us) hides their latency
            float xr[4], xz[4], xn[4];
            #pragma unroll
            for (int reg = 0; reg < 4; ++reg) {
                const float* xgp = xgR + ((size_t)s * 128 + b_base + reg) * 1536 + u;
                xr[reg] = xgp[0]; xz[reg] = xgp[512]; xn[reg] = xgp[1024];
            }

            union { unsigned long long u8[2]; shortx8 v; } af[16];
            if (kg > 0) {
                const unsigned int* fp = cnt + ((size_t)(kg - 1) * 4 + bg) * CNT_STRIDE;
                while (__hip_atomic_load(fp, __ATOMIC_RELAXED, __HIP_MEMORY_SCOPE_AGENT) < 16u)
                    __builtin_amdgcn_s_sleep(1);
                const unsigned short* hsrc = hb + (size_t)((kg - 1) & 1) * (128 * 512)
                                                + (size_t)(b0 + mt * 16 + l16) * 512 + quad * 8;
                #pragma unroll
                for (int kt = 0; kt < 16; ++kt) {
                    af[kt].u8[0] = __hip_atomic_load((const unsigned long long*)(hsrc + kt * 32),
                                                     __ATOMIC_RELAXED, __HIP_MEMORY_SCOPE_AGENT);
                    af[kt].u8[1] = __hip_atomic_load((const unsigned long long*)(hsrc + kt * 32 + 4),
                                                     __ATOMIC_RELAXED, __HIP_MEMORY_SCOPE_AGENT);
                }
            } else {
                #pragma unroll
                for (int kt = 0; kt < 16; ++kt) { af[kt].u8[0] = 0ull; af[kt].u8[1] = 0ull; }
            }

            floatx4 aR = {0,0,0,0}, aZ = {0,0,0,0}, aN = {0,0,0,0};
            #pragma unroll
            for (int kt = 0; kt < 16; ++kt) {
                aR = __builtin_amdgcn_mfma_f32_16x16x32_bf16(af[kt].v, w[0][kt], aR, 0, 0, 0);
                aZ = __builtin_amdgcn_mfma_f32_16x16x32_bf16(af[kt].v, w[1][kt], aZ, 0, 0, 0);
                aN = __builtin_amdgcn_mfma_f32_16x16x32_bf16(af[kt].v, w[2][kt], aN, 0, 0, 0);
            }

            unsigned short* hdst = hb + (size_t)(kg & 1) * (128 * 512);
            #pragma unroll
            for (int reg = 0; reg < 4; ++reg) {
                const float r = 1.f / (1.f + __expf(-(xr[reg] + aR[reg] + bhr)));
                const float z = 1.f / (1.f + __expf(-(xz[reg] + aZ[reg] + bhz)));
                const float n = tanhf(xn[reg] + r * (aN[reg] + bhn));
                const float h = (1.f - z) * n + z * hp[reg];
                hp[reg] = h;
                const float h_odd = __shfl_xor(h, 1);
                if (!(lane & 1)) {
                    unsigned int pk = (unsigned int)f2bf(h) | ((unsigned int)f2bf(h_odd) << 16);
                    __hip_atomic_store((unsigned int*)(hdst + (size_t)(b_base + reg) * 512 + u),
                                       pk, __ATOMIC_RELAXED, __HIP_MEMORY_SCOPE_AGENT);
                }
                if (kg == 511) out[(size_t)(b_base + reg) * 512 + u] = h;
            }
            __syncthreads();   // vmcnt(0): all 4 waves' publishes acked at LLC before flag
            if (t == 0)
                __hip_atomic_fetch_add(cnt + ((size_t)kg * 4 + bg) * CNT_STRIDE, 1u,
                                       __ATOMIC_RELAXED, __HIP_MEMORY_SCOPE_AGENT);
        }

        #pragma unroll
        for (int reg = 0; reg < 4; ++reg)
            hstate[(size_t)(b_base + reg) * 512 + u] = hp[reg];
        return;
    }

    // ================= GEMM ROLE: x-gates for the NEXT chunk =================
    if (!do_gemm) return;
    const int NG = do_rec ? 192 : 256;
    const int gid = do_rec ? bx - 64 : bx;

    for (int T = gid; T < 1536; T += NG) {       // 24 g-tiles x 64 m-tiles
        const int g0 = (T % 24) * 64;
        const int m0 = (T / 24) * 64;            // chunk-local m = kc*128 + b
        const int kc = m0 >> 7;
        const int b0 = m0 & 127;
        const int kg = gemm_kg0 + kc;

        floatx4 acc[4] = {{0,0,0,0},{0,0,0,0},{0,0,0,0},{0,0,0,0}};

        for (int ki = 0; ki < 16; ++ki) {
            const int i0 = ki * 32;
            #pragma unroll
            for (int rep = 0; rep < 2; ++rep) {
                const int r = (t >> 3) + rep * 32;
                const int c = (t & 7) * 4;
                float4 av = *(const float4*)(vis + ((size_t)(b0 + r) * 512 + kg) * 512 + i0 + c);
                ushort4 ab; ab.x = f2bf(av.x); ab.y = f2bf(av.y); ab.z = f2bf(av.z); ab.w = f2bf(av.w);
                *(ushort4*)&Ast[r][c] = ab;
                float4 bv = *(const float4*)(Wih + (size_t)(g0 + r) * 512 + i0 + c);
                ushort4 bb; bb.x = f2bf(bv.x); bb.y = f2bf(bv.y); bb.z = f2bf(bv.z); bb.w = f2bf(bv.w);
                *(ushort4*)&Bst[r][c] = bb;
            }
            __syncthreads();
            shortx8 afr = *(const shortx8*)(&Ast[wave * 16 + l16][quad * 8]);
            #pragma unroll
            for (int nb = 0; nb < 4; ++nb) {
                shortx8 bfr = *(const shortx8*)(&Bst[nb * 16 + l16][quad * 8]);
                acc[nb] = __builtin_amdgcn_mfma_f32_16x16x32_bf16(afr, bfr, acc[nb], 0, 0, 0);
            }
            __syncthreads();
        }
        #pragma unroll
        for (int nb = 0; nb < 4; ++nb) {
            const int g = g0 + nb * 16 + l16;
            const float bi = bih[g];
            #pragma unroll
            for (int reg = 0; reg < 4; ++reg) {
                const int m = m0 + wave * 16 + quad * 4 + reg;
                xgW[(size_t)m * 1536 + g] = acc[nb][reg] + bi;
            }
        }
    }
}

extern "C" void kernel_launch(void* const* d_in, const int* in_sizes, int n_in,
                              void* d_out, int out_size, void* d_ws, size_t ws_size,
                              hipStream_t stream) {
    const float* vis = (const float*)d_in[0];
    const float* Wih = (const float*)d_in[1];
    const float* Whh = (const float*)d_in[2];
    const float* bih = (const float*)d_in[3];
    const float* bhh = (const float*)d_in[4];
    float* out = (float*)d_out;

    char* ws = (char*)d_ws;
    float* xg0 = (float*)ws;
    float* xg1 = (float*)(ws + XG_BYTES);
    unsigned short* hb = (unsigned short*)(ws + 2 * XG_BYTES);
    float* hstate = (float*)(ws + 2 * XG_BYTES + HB_BYTES);
    unsigned int* cnt = (unsigned int*)(ws + 2 * XG_BYTES + HB_BYTES + HSTATE_BYTES);

    hipMemsetAsync(cnt, 0, CNT_BYTES, stream);

    float* bufs[2] = {xg0, xg1};

    // dispatch 0: GEMM only -> chunk 0 into xg0
    gru_fused<<<256, 256, 0, stream>>>(vis, Wih, bih, Whh, bhh,
                                       xg0, xg0, hb, hstate, cnt, out,
                                       0, 0, 0, 1);
    // fused dispatches: rec chunk i (reads bufs[i&1]) + gemm chunk i+1 (writes bufs[(i+1)&1])
    for (int i = 0; i < 16; ++i) {
        gru_fused<<<256, 256, 0, stream>>>(vis, Wih, bih, Whh, bhh,
                                           bufs[i & 1], bufs[(i + 1) & 1],
                                           hb, hstate, cnt, out,
                                           i * CH, (i + 1) * CH, 1, (i < 15) ? 1 : 0);
    }
}